// Round 1
// baseline (113.378 us; speedup 1.0000x reference)
//
#include <hip/hip_runtime.h>

#define GQ   8192            // bs(32) * Gn(256)
#define WPB  2               // waves per block (2 consecutive groups share 128B lines)
#define MROW 132             // M row stride in floats (128 + 4: rows shift 4 banks)
#define SLICE 1280           // per-wave LDS floats: M 9x132=1188 + SIMM 81 + pad

// One wave per group, short program, minimal serial chains:
//  - label/index logic via shuffles + ballots (no scalar pipeline, no LDS)
//  - bucket means via 16 uniform switch dispatches (readlane -> scalar branch)
//  - lane l owns channels (l, l+64), loaded straight to registers
//  - only 2 block barriers (M exchange, SIMM exchange)
__global__ __launch_bounds__(64 * WPB, 6) void group_loss_kernel(
    const int*   __restrict__ labs,   // [G*16]
    const float* __restrict__ feats,  // [32,128,256,16]
    const int*   __restrict__ idxs,   // [G*16]
    const float* __restrict__ ctx,    // [128]
    float2* __restrict__ ws)          // [G] {gl*gv, gv}
{
    __shared__ float SH[WPB * SLICE];           // 10240 B -> LDS allows 16 blocks/CU

    const int l  = threadIdx.x & 63;
    const int wu = threadIdx.x >> 6;
    float* MM   = SH + wu * SLICE;              // 9 x 132
    float* SIMM = MM + 9 * MROW;                // 81

    const int blk = blockIdx.x;
    // XCD blk&7 owns contiguous groups [x*1024, (x+1)*1024); block = gn pair
    const int g  = ((blk & 7) << 10) | ((blk >> 3) << 1) | wu;
    const int b  = g >> 8;
    const int gn = g & 255;
    const long fbase = (long)b * (128 * 256 * 16) + (long)gn * 16;

    // ---- feature columns straight to registers (lane l -> channels l, l+64)
    const float* gp0 = feats + fbase + (long)l * 4096;
    const float* gp1 = gp0 + 64 * 4096;
    float4 A[4], B[4];
    #pragma unroll
    for (int q = 0; q < 4; ++q) A[q] = *(const float4*)(gp0 + q * 4);
    #pragma unroll
    for (int q = 0; q < 4; ++q) B[q] = *(const float4*)(gp1 + q * 4);
    const float cx0 = ctx[l], cx1 = ctx[l + 64];
    float fa[16], fb[16];
    #pragma unroll
    for (int q = 0; q < 4; ++q) {
        fa[4*q+0] = A[q].x; fa[4*q+1] = A[q].y; fa[4*q+2] = A[q].z; fa[4*q+3] = A[q].w;
        fb[4*q+0] = B[q].x; fb[4*q+1] = B[q].y; fb[4*q+2] = B[q].z; fb[4*q+3] = B[q].w;
    }

    // ---- label/index logic: lanes 0..15 hold sample s=l ---------------------
    int myidx = -1, mylab = -2;
    if (l < 16) { myidx = idxs[g * 16 + l]; mylab = labs[g * 16 + l]; }

    // u = count of distinct seed indices (first-occurrence positions)
    bool dup = false;
    #pragma unroll
    for (int j = 0; j < 15; ++j) {
        const int vj = __shfl(myidx, j);
        dup = dup || ((l > j) && (myidx == vj));
    }
    const int u = __popcll(__ballot((l < 16) && !dup));

    const bool valid = l < u;                   // u<=16, lanes>=16 invalid
    const int bid = valid ? (mylab + 1) : 255;  // bucket 0 = bg(-1), 1..8 = fg

    unsigned long long memb[9]; int cnt[9];
    #pragma unroll
    for (int r = 0; r < 9; ++r) {
        memb[r] = __ballot(bid == r);
        cnt[r]  = __popcll(memb[r]);
    }
    const bool has_bg = cnt[0] > 0;
    int fg_count = 0, pm = 0;
    #pragma unroll
    for (int r = 1; r < 9; ++r)
        if (cnt[r] > 0) { ++fg_count; pm |= 1 << r; }

    // ---- bucket sums: 16 uniform dispatches (readlane -> scalar switch) ----
    float m0[9] = {0,0,0,0,0,0,0,0,0};
    float m1[9] = {0,0,0,0,0,0,0,0,0};
    #pragma unroll
    for (int s = 0; s < 16; ++s) {
        if (s < u) {                                        // uniform compare
            const int bs = __builtin_amdgcn_readlane(bid, s); // uniform 0..8
            switch (bs) {
                case 0: m0[0] += fa[s]; m1[0] += fb[s]; break;
                case 1: m0[1] += fa[s]; m1[1] += fb[s]; break;
                case 2: m0[2] += fa[s]; m1[2] += fb[s]; break;
                case 3: m0[3] += fa[s]; m1[3] += fb[s]; break;
                case 4: m0[4] += fa[s]; m1[4] += fb[s]; break;
                case 5: m0[5] += fa[s]; m1[5] += fb[s]; break;
                case 6: m0[6] += fa[s]; m1[6] += fb[s]; break;
                case 7: m0[7] += fa[s]; m1[7] += fb[s]; break;
                case 8: m0[8] += fa[s]; m1[8] += fb[s]; break;
            }
        }
    }
    #pragma unroll
    for (int r = 0; r < 9; ++r) {
        const float invc = 1.0f / (float)(cnt[r] > 0 ? cnt[r] : 1);
        m0[r] *= invc; m1[r] *= invc;
    }
    if (!has_bg) { m0[0] = cx0; m1[0] = cx1; }  // row 0 = context_compen

    // ---- M -> LDS (2-way bank aliasing = free) -----------------------------
    #pragma unroll
    for (int r = 0; r < 9; ++r) {
        MM[r * MROW + l]      = m0[r];
        MM[r * MROW + 64 + l] = m1[r];
    }
    __syncthreads();

    // ---- 44 pairs (i,j), 1<=i<=8, 0<=j<=i: lane p dots rows i,j over 128 ch
    float simv = 0.0f; int pi = 0, pj = 0;
    if (l < 44) {
        pi = (int)((sqrtf(8.0f * (float)l + 9.0f) - 1.0f) * 0.5f);
        pj = l - (pi * (pi + 1) / 2 - 1);
        const float* Ri = MM + pi * MROW;
        const float* Rj = MM + pj * MROW;
        float acc = 0.0f;
        #pragma unroll
        for (int q = 0; q < 32; ++q) {
            float4 x = *(const float4*)(Ri + 4 * q);
            float4 y = *(const float4*)(Rj + 4 * q);
            acc += x.x * y.x + x.y * y.y + x.z * y.z + x.w * y.w;
        }
        simv = acc * 5.0f;                      // 1/T
    }
    if (l < 44) {
        SIMM[pi * 9 + pj] = simv;
        if (pi != pj) SIMM[pj * 9 + pi] = simv;
    }
    __syncthreads();

    // ---- masked logsumexp per present fg row (lane r = row r) --------------
    float li_val = 0.0f;
    if (l >= 1 && l < 9 && ((pm >> l) & 1)) {
        float srow[9];
        #pragma unroll
        for (int j = 0; j < 9; ++j) srow[j] = SIMM[l * 9 + j];
        float vmax = srow[0];                   // col 0 (bg/ctx) always valid
        #pragma unroll
        for (int j = 1; j < 9; ++j)
            if ((pm >> j) & 1) vmax = fmaxf(vmax, srow[j]);
        float se = __expf(srow[0] - vmax);
        #pragma unroll
        for (int j = 1; j < 9; ++j)
            if ((pm >> j) & 1) se += __expf(srow[j] - vmax);
        li_val = vmax + __logf(se) - srow[l];
    }

    // ---- sum li over lanes 1..8; single float2 store -----------------------
    float ssum = li_val;
    #pragma unroll
    for (int off = 8; off >= 1; off >>= 1) ssum += __shfl_down(ssum, off);
    if (l == 0) {
        float2 r;
        r.x = ssum / (float)(fg_count > 0 ? fg_count : 1);  // gl*gv
        r.y = (fg_count > 0) ? 1.0f : 0.0f;                 // gv
        ws[g] = r;
    }
}

// Deterministic 8192 -> 1 reduction
__global__ __launch_bounds__(1024) void reduce_kernel(
    const float2* __restrict__ ws, float* __restrict__ out)
{
    __shared__ float sa[1024], sb[1024];
    const int t = threadIdx.x;
    float a = 0.0f, b2 = 0.0f;
    for (int g = t; g < GQ; g += 1024) {
        float2 v = ws[g];
        a += v.x; b2 += v.y;
    }
    sa[t] = a; sb[t] = b2;
    __syncthreads();
    for (int off = 512; off > 0; off >>= 1) {
        if (t < off) { sa[t] += sa[t + off]; sb[t] += sb[t + off]; }
        __syncthreads();
    }
    if (t == 0) out[0] = 0.1f * (sa[0] / sb[0]);
}

extern "C" void kernel_launch(void* const* d_in, const int* in_sizes, int n_in,
                              void* d_out, int out_size, void* d_ws, size_t ws_size,
                              hipStream_t stream) {
    const int*   labs  = (const int*)d_in[0];    // proposal_instance_mask
    const float* feats = (const float*)d_in[1];  // grouped_features
    const int*   idxs  = (const int*)d_in[2];    // grouped_indices
    const float* ctx   = (const float*)d_in[3];  // context_compen
    float* out = (float*)d_out;
    float2* ws = (float2*)d_ws;

    group_loss_kernel<<<GQ / WPB, 64 * WPB, 0, stream>>>(labs, feats, idxs, ctx, ws);
    reduce_kernel<<<1, 1024, 0, stream>>>(ws, out);
}